// Round 17
// baseline (160.877 us; speedup 1.0000x reference)
//
#include <hip/hip_runtime.h>

#define NF   784
#define ZD   64
#define BXN  256
#define BZN  4096
#define KDIM 3136    // 4*NF
#define LCOL 1568    // 2*NF logit columns

typedef __attribute__((ext_vector_type(8))) short bf16x8;
typedef __attribute__((ext_vector_type(4))) float f32x4;
typedef __attribute__((ext_vector_type(8))) unsigned short ushort8;
typedef __attribute__((ext_vector_type(4))) unsigned short us4;   // clang vector: nontemporal-ok

__device__ __forceinline__ unsigned short f2bf(float f) {
  unsigned u = __float_as_uint(f);
  u += 0x7fff + ((u >> 16) & 1);   // round-to-nearest-even
  return (unsigned short)(u >> 16);
}

// v_cvt_pk_bf16_f32: pack 2 f32 -> 2 bf16 (RNE) in one VALU op (no builtin; m240)
__device__ __forceinline__ unsigned pkbf(float a, float b) {
  unsigned r;
  asm("v_cvt_pk_bf16_f32 %0, %1, %2" : "=v"(r) : "v"(a), "v"(b));
  return r;
}

// ---------------- Kernel 1: prep (build_a + W transpose + zero counters) ----------------
__global__ __launch_bounds__(256) void prep(const float* __restrict__ x,
                                            const float* __restrict__ W,
                                            const int* __restrict__ tree,
                                            unsigned short* __restrict__ Amat,
                                            unsigned short* __restrict__ Wt,
                                            int* __restrict__ counters) {
  int bid = blockIdx.x, tid = threadIdx.x;
  if (bid < 1024) {                       // ---- build_a
    int b = bid >> 2;
    int j = (bid & 3) * 256 + tid;
    if (j >= NF) return;
    float xb = x[b * NF + j];
    int idx = tree[j];
    int gidx = idx < 0 ? idx + NF : idx;  // JAX negative-index wrap
    float xt = x[b * NF + gidx];
    ushort4 v;
    v.x = f2bf((1.f - xt) * xb);
    v.y = f2bf(xt * xb);
    v.z = f2bf((1.f - xt) * (1.f - xb));
    v.w = f2bf(xt * (1.f - xb));
    *(ushort4*)&Amat[(size_t)b * KDIM + 4 * j] = v;
  } else if (bid < 1122) {                // ---- W -> Wt (transpose), 98 blocks
    int t = (bid - 1024) * 256 + tid;     // 0..25087
    int c = t >> 4, k0 = (t & 15) * 4;
    ushort4 o;
    o.x = f2bf(W[(k0 + 0) * LCOL + c]);
    o.y = f2bf(W[(k0 + 1) * LCOL + c]);
    o.z = f2bf(W[(k0 + 2) * LCOL + c]);
    o.w = f2bf(W[(k0 + 3) * LCOL + c]);
    *(ushort4*)&Wt[c * 64 + k0] = o;
  } else {                                // ---- zero the 64 nt counters (replay-safe)
    if (tid < 64) counters[tid] = 0;
  }
}

// ---------------- Kernel 2: FUSED logits+logsigmoid+GEMM + counter-gated reduce tail ----------------
// R15 structure (best: 37.06us): 512 blocks (64 nt x 8 ks) x 256 thr (4 waves).
// NEW: last-arriving block per nt (device-scope atomic counter) reduces the 8 bf16
// partial slices into f32 out -> reduce8 kernel + one launch gap eliminated.
#define LP 40
__global__ __launch_bounds__(256) void gemm_fused(const unsigned short* __restrict__ Amat,
                                                  const float* __restrict__ z,
                                                  const unsigned short* __restrict__ Wt,
                                                  const float* __restrict__ bias,
                                                  const int* __restrict__ tree,
                                                  unsigned short* __restrict__ part,
                                                  int* __restrict__ counters,
                                                  float* __restrict__ out) {
  __shared__ unsigned short As[2][256][LP];  // 40960 B
  __shared__ unsigned short Bs[2][64][LP];   // 10240 B
  int bid = blockIdx.x;                      // 512 = 64 n-tiles x 8 k-splits
  int s = bid & 7, nt = bid >> 3;
  int n0 = nt * 64;
  int kt0 = s * 12 + (s < 2 ? s : 2);        // 98 = 13+13+12*6
  int nsteps = (s < 2) ? 13 : 12;
  int ktend = kt0 + nsteps;
  int tid = threadIdx.x;
  int w = tid >> 6, lane = tid & 63;
  int fr = lane & 15, hi = lane >> 4, kq = hi * 8;
  int srow = tid >> 2, scol = (tid & 3) * 8;
  const unsigned short* Ag = Amat + (size_t)srow * KDIM + scol;

  // z fragments: this wave's 16 z-rows, packed f32->bf16 in-register.
  const float* zpf = z + (size_t)(n0 + w * 16 + fr) * 64 + kq;
  float4 zl0 = *(const float4*)(zpf);
  float4 zl1 = *(const float4*)(zpf + 4);
  float4 zl2 = *(const float4*)(zpf + 32);
  float4 zl3 = *(const float4*)(zpf + 36);
  union { unsigned u[4]; bf16x8 v; } Z0, Z1;
  Z0.u[0] = pkbf(zl0.x, zl0.y); Z0.u[1] = pkbf(zl0.z, zl0.w);
  Z0.u[2] = pkbf(zl1.x, zl1.y); Z0.u[3] = pkbf(zl1.z, zl1.w);
  Z1.u[0] = pkbf(zl2.x, zl2.y); Z1.u[1] = pkbf(zl2.z, zl2.w);
  Z1.u[2] = pkbf(zl3.x, zl3.y); Z1.u[3] = pkbf(zl3.z, zl3.w);
  bf16x8 zf0 = Z0.v, zf1 = Z1.v;

  f32x4 acc[4][4];
#pragma unroll
  for (int m = 0; m < 4; ++m)
#pragma unroll
    for (int n = 0; n < 4; ++n) acc[m][n] = (f32x4){0.f, 0.f, 0.f, 0.f};

  // ---- prologue: load step kt0's registers
  const unsigned short* wp = Wt + (size_t)(kt0 * 16 + fr) * 64 + kq;
  bf16x8 wf0 = *(const bf16x8*)wp;
  bf16x8 wf1 = *(const bf16x8*)(wp + 32);
  float4 b4  = *(const float4*)&bias[kt0 * 16 + 4 * hi];
  int2   tr2 = *(const int2*)&tree[kt0 * 8 + 2 * hi];
  int k0 = kt0 * 32;
  float4 ar0 = *(const float4*)(Ag + k0);
  float4 ar1 = *(const float4*)(Ag + (size_t)64 * KDIM + k0);
  float4 ar2 = *(const float4*)(Ag + (size_t)128 * KDIM + k0);
  float4 ar3 = *(const float4*)(Ag + (size_t)192 * KDIM + k0);

  int buf = 0;
  for (int i = 0; i < nsteps; ++i) {
    int kt = kt0 + i;
    f32x4 lacc = (f32x4){0.f, 0.f, 0.f, 0.f};
    lacc = __builtin_amdgcn_mfma_f32_16x16x32_bf16(wf0, zf0, lacc, 0, 0, 0);
    lacc = __builtin_amdgcn_mfma_f32_16x16x32_bf16(wf1, zf1, lacc, 0, 0, 0);
    int ktn = (kt + 1 < ktend) ? kt + 1 : kt;
    const unsigned short* wpn = Wt + (size_t)(ktn * 16 + fr) * 64 + kq;
    bf16x8 wfn0 = *(const bf16x8*)wpn;
    bf16x8 wfn1 = *(const bf16x8*)(wpn + 32);
    float4 b4n  = *(const float4*)&bias[ktn * 16 + 4 * hi];
    int2   tr2n = *(const int2*)&tree[ktn * 8 + 2 * hi];
    int k0n = ktn * 32;
    float4 arn0 = *(const float4*)(Ag + k0n);
    float4 arn1 = *(const float4*)(Ag + (size_t)64 * KDIM + k0n);
    float4 arn2 = *(const float4*)(Ag + (size_t)128 * KDIM + k0n);
    float4 arn3 = *(const float4*)(Ag + (size_t)192 * KDIM + k0n);
    float bb[4] = { b4.x, b4.y, b4.z, b4.w };
    int tt[2] = { tr2.x, tr2.y };
    union { unsigned u[4]; ushort8 v; } V;
#pragma unroll
    for (int p = 0; p < 2; ++p) {
      float l1 = lacc[2 * p + 1] + bb[2 * p + 1];
      float l0 = (tt[p] == -1) ? l1 : (lacc[2 * p] + bb[2 * p]);
      // logsig(v) = v>=0 ? -log(1+e^-v) : v - log(1+e^v);  logsig(-v) = logsig(v) - v
      float e0 = __expf(-fabsf(l0)); float sp0 = __logf(1.f + e0);
      float ls0 = (l0 >= 0.f) ? -sp0 : l0 - sp0;
      float e1 = __expf(-fabsf(l1)); float sp1 = __logf(1.f + e1);
      float ls1 = (l1 >= 0.f) ? -sp1 : l1 - sp1;
      V.u[2 * p + 0] = pkbf(ls0, ls1);           // [ls0, ls1]
      V.u[2 * p + 1] = pkbf(ls0 - l0, ls1 - l1); // [lsn0, lsn1]
    }
    *(float4*)&As[buf][srow      ][scol] = ar0;
    *(float4*)&As[buf][srow +  64][scol] = ar1;
    *(float4*)&As[buf][srow + 128][scol] = ar2;
    *(float4*)&As[buf][srow + 192][scol] = ar3;
    *(ushort8*)&Bs[buf][w * 16 + fr][kq] = V.v;
    __syncthreads();          // single barrier: dbuf makes write(k+1) race-free
    bf16x8 a[4], b[4];
#pragma unroll
    for (int m = 0; m < 4; ++m) a[m] = *(const bf16x8*)&As[buf][w * 64 + m * 16 + fr][kq];
#pragma unroll
    for (int n = 0; n < 4; ++n) b[n] = *(const bf16x8*)&Bs[buf][n * 16 + fr][kq];
#pragma unroll
    for (int m = 0; m < 4; ++m)
#pragma unroll
      for (int n = 0; n < 4; ++n)
        acc[m][n] = __builtin_amdgcn_mfma_f32_16x16x32_bf16(a[m], b[n], acc[m][n], 0, 0, 0);
    wf0 = wfn0; wf1 = wfn1; b4 = b4n; tr2 = tr2n;
    ar0 = arn0; ar1 = arn1; ar2 = arn2; ar3 = arn3;
    buf ^= 1;
  }
  // ---- partial store: col = lane&15 (n), row = (lane>>4)*4 + reg (m). bf16, nt.
  int col = lane & 15, rq = hi * 4;
  unsigned short* Pp = part + (size_t)s * (256 * 4096) + (size_t)(w * 64) * 4096 + n0;
#pragma unroll
  for (int m = 0; m < 4; ++m)
#pragma unroll
    for (int n = 0; n < 4; ++n)
#pragma unroll
      for (int r = 0; r < 4; ++r)
        __builtin_nontemporal_store(f2bf(acc[m][n][r]),
                                    &Pp[(m * 16 + rq + r) * 4096 + n * 16 + col]);

  // ---- counter-gated tail: last block per nt reduces its 64-column slice.
  __threadfence();                        // partials visible device-wide before count
  __shared__ int lastFlag;
  if (tid == 0) lastFlag = (atomicAdd(&counters[nt], 1) == 7);
  __syncthreads();
  if (lastFlag) {
    __threadfence();                      // acquire: counter==7 -> all partials visible
    for (int idx = tid; idx < 4096; idx += 256) {   // 256 rows x 16 col-quads
      int m = idx >> 4, c4 = idx & 15;
      size_t off = (size_t)m * 4096 + n0 + c4 * 4;
      f32x4 ssum = (f32x4){0.f, 0.f, 0.f, 0.f};
#pragma unroll
      for (int q = 0; q < 8; ++q) {
        us4 v = __builtin_nontemporal_load((const us4*)&part[(size_t)q * (256 * 4096) + off]);
        ssum[0] += __uint_as_float((unsigned)v[0] << 16);
        ssum[1] += __uint_as_float((unsigned)v[1] << 16);
        ssum[2] += __uint_as_float((unsigned)v[2] << 16);
        ssum[3] += __uint_as_float((unsigned)v[3] << 16);
      }
      __builtin_nontemporal_store(ssum, (f32x4*)&out[off]);
    }
  }
}

extern "C" void kernel_launch(void* const* d_in, const int* in_sizes, int n_in,
                              void* d_out, int out_size, void* d_ws, size_t ws_size,
                              hipStream_t stream) {
  const float* x    = (const float*)d_in[0];
  const float* z    = (const float*)d_in[1];
  const float* W    = (const float*)d_in[2];
  const float* bias = (const float*)d_in[3];
  const int*   tree = (const int*)d_in[4];
  float* out = (float*)d_out;

  unsigned short* Amat = (unsigned short*)d_ws;                     //  1,605,632 B
  unsigned short* Wt   = (unsigned short*)((char*)d_ws + 1605632);  //    200,704 B
  unsigned short* part = (unsigned short*)((char*)d_ws + 1806336);  // 16,777,216 B (bf16)
  int*            counters = (int*)((char*)d_ws + 18583552);        //        256 B

  prep<<<dim3(1123), 256, 0, stream>>>(x, W, tree, Amat, Wt, counters);
  gemm_fused<<<dim3(512), 256, 0, stream>>>(Amat, z, Wt, bias, tree, part, counters, out);
}

// Round 18
// 36.937 us; speedup vs baseline: 4.3555x; 4.3555x over previous
//
#include <hip/hip_runtime.h>

#define NF   784
#define ZD   64
#define BXN  256
#define BZN  4096
#define KDIM 3136    // 4*NF
#define LCOL 1568    // 2*NF logit columns

typedef __attribute__((ext_vector_type(8))) short bf16x8;
typedef __attribute__((ext_vector_type(4))) float f32x4;
typedef __attribute__((ext_vector_type(8))) unsigned short ushort8;
typedef __attribute__((ext_vector_type(4))) unsigned short us4;   // clang vector: nontemporal-ok

__device__ __forceinline__ unsigned short f2bf(float f) {
  unsigned u = __float_as_uint(f);
  u += 0x7fff + ((u >> 16) & 1);   // round-to-nearest-even
  return (unsigned short)(u >> 16);
}

// v_cvt_pk_bf16_f32: pack 2 f32 -> 2 bf16 (RNE) in one VALU op (no builtin; m240)
__device__ __forceinline__ unsigned pkbf(float a, float b) {
  unsigned r;
  asm("v_cvt_pk_bf16_f32 %0, %1, %2" : "=v"(r) : "v"(a), "v"(b));
  return r;
}

// ---------------- Kernel 1: prep (build_a + W transpose) ----------------
__global__ __launch_bounds__(256) void prep(const float* __restrict__ x,
                                            const float* __restrict__ W,
                                            const int* __restrict__ tree,
                                            unsigned short* __restrict__ Amat,
                                            unsigned short* __restrict__ Wt) {
  int bid = blockIdx.x, tid = threadIdx.x;
  if (bid < 1024) {                       // ---- build_a
    int b = bid >> 2;
    int j = (bid & 3) * 256 + tid;
    if (j >= NF) return;
    float xb = x[b * NF + j];
    int idx = tree[j];
    int gidx = idx < 0 ? idx + NF : idx;  // JAX negative-index wrap
    float xt = x[b * NF + gidx];
    ushort4 v;
    v.x = f2bf((1.f - xt) * xb);
    v.y = f2bf(xt * xb);
    v.z = f2bf((1.f - xt) * (1.f - xb));
    v.w = f2bf(xt * (1.f - xb));
    *(ushort4*)&Amat[(size_t)b * KDIM + 4 * j] = v;
  } else {                                // ---- W -> Wt (transpose), 98 blocks
    int t = (bid - 1024) * 256 + tid;     // 0..25087
    int c = t >> 4, k0 = (t & 15) * 4;
    ushort4 o;
    o.x = f2bf(W[(k0 + 0) * LCOL + c]);
    o.y = f2bf(W[(k0 + 1) * LCOL + c]);
    o.z = f2bf(W[(k0 + 2) * LCOL + c]);
    o.w = f2bf(W[(k0 + 3) * LCOL + c]);
    *(ushort4*)&Wt[c * 64 + k0] = o;
  }
}

// ---------------- Kernel 2: FUSED gemm, B produced ONE STEP AHEAD ----------------
// R15 shape (512 blk x 4 waves). NEW schedule per step i:
//   stage As/Bs from regs (V(i) precomputed) -> prefetch A(i+1) -> barrier ->
//   logit MFMA(i+1) + logsig(i+1) INTERLEAVED with 16 main MFMA (VALU/matrix
//   dual-pipe co-issue, m114) -> rotate. Transcendentals leave the critical path.
#define LP 40
__global__ __launch_bounds__(256) void gemm_fused(const unsigned short* __restrict__ Amat,
                                                  const float* __restrict__ z,
                                                  const unsigned short* __restrict__ Wt,
                                                  const float* __restrict__ bias,
                                                  const int* __restrict__ tree,
                                                  unsigned short* __restrict__ part) {
  __shared__ unsigned short As[2][256][LP];  // 40960 B
  __shared__ unsigned short Bs[2][64][LP];   // 10240 B
  int bid = blockIdx.x;                      // 512 = 64 n-tiles x 8 k-splits
  int s = bid & 7, nt = bid >> 3;
  int n0 = nt * 64;
  int kt0 = s * 12 + (s < 2 ? s : 2);        // 98 = 13+13+12*6
  int nsteps = (s < 2) ? 13 : 12;
  int ktend = kt0 + nsteps;
  int tid = threadIdx.x;
  int w = tid >> 6, lane = tid & 63;
  int fr = lane & 15, hi = lane >> 4, kq = hi * 8;
  int srow = tid >> 2, scol = (tid & 3) * 8;
  const unsigned short* Ag = Amat + (size_t)srow * KDIM + scol;

  // z fragments: this wave's 16 z-rows, packed f32->bf16 in-register.
  const float* zpf = z + (size_t)(n0 + w * 16 + fr) * 64 + kq;
  float4 zl0 = *(const float4*)(zpf);
  float4 zl1 = *(const float4*)(zpf + 4);
  float4 zl2 = *(const float4*)(zpf + 32);
  float4 zl3 = *(const float4*)(zpf + 36);
  union { unsigned u[4]; bf16x8 v; } Z0, Z1;
  Z0.u[0] = pkbf(zl0.x, zl0.y); Z0.u[1] = pkbf(zl0.z, zl0.w);
  Z0.u[2] = pkbf(zl1.x, zl1.y); Z0.u[3] = pkbf(zl1.z, zl1.w);
  Z1.u[0] = pkbf(zl2.x, zl2.y); Z1.u[1] = pkbf(zl2.z, zl2.w);
  Z1.u[2] = pkbf(zl3.x, zl3.y); Z1.u[3] = pkbf(zl3.z, zl3.w);
  bf16x8 zf0 = Z0.v, zf1 = Z1.v;

  f32x4 acc[4][4];
#pragma unroll
  for (int m = 0; m < 4; ++m)
#pragma unroll
    for (int n = 0; n < 4; ++n) acc[m][n] = (f32x4){0.f, 0.f, 0.f, 0.f};

  // ---- prologue: V(kt0) computed up front; W/bias/tree advanced to kt0+1
  ushort8 V;
  {
    const unsigned short* wpp = Wt + (size_t)(kt0 * 16 + fr) * 64 + kq;
    bf16x8 pwf0 = *(const bf16x8*)wpp;
    bf16x8 pwf1 = *(const bf16x8*)(wpp + 32);
    float4 pb4  = *(const float4*)&bias[kt0 * 16 + 4 * hi];
    int2   ptr2 = *(const int2*)&tree[kt0 * 8 + 2 * hi];
    f32x4 lacc = (f32x4){0.f, 0.f, 0.f, 0.f};
    lacc = __builtin_amdgcn_mfma_f32_16x16x32_bf16(pwf0, zf0, lacc, 0, 0, 0);
    lacc = __builtin_amdgcn_mfma_f32_16x16x32_bf16(pwf1, zf1, lacc, 0, 0, 0);
    float bb[4] = { pb4.x, pb4.y, pb4.z, pb4.w };
    int tt[2] = { ptr2.x, ptr2.y };
    union { unsigned u[4]; ushort8 v; } VV;
#pragma unroll
    for (int p = 0; p < 2; ++p) {
      float l1 = lacc[2 * p + 1] + bb[2 * p + 1];
      float l0 = (tt[p] == -1) ? l1 : (lacc[2 * p] + bb[2 * p]);
      float e0 = __expf(-fabsf(l0)); float sp0 = __logf(1.f + e0);
      float ls0 = (l0 >= 0.f) ? -sp0 : l0 - sp0;
      float e1 = __expf(-fabsf(l1)); float sp1 = __logf(1.f + e1);
      float ls1 = (l1 >= 0.f) ? -sp1 : l1 - sp1;
      VV.u[2 * p + 0] = pkbf(ls0, ls1);
      VV.u[2 * p + 1] = pkbf(ls0 - l0, ls1 - l1);
    }
    V = VV.v;
  }
  int k0 = kt0 * 32;
  float4 ar0 = *(const float4*)(Ag + k0);
  float4 ar1 = *(const float4*)(Ag + (size_t)64 * KDIM + k0);
  float4 ar2 = *(const float4*)(Ag + (size_t)128 * KDIM + k0);
  float4 ar3 = *(const float4*)(Ag + (size_t)192 * KDIM + k0);
  int kt1 = (kt0 + 1 < ktend) ? kt0 + 1 : ktend - 1;
  const unsigned short* wp1 = Wt + (size_t)(kt1 * 16 + fr) * 64 + kq;
  bf16x8 wf0 = *(const bf16x8*)wp1;
  bf16x8 wf1 = *(const bf16x8*)(wp1 + 32);
  float4 b4  = *(const float4*)&bias[kt1 * 16 + 4 * hi];
  int2   tr2 = *(const int2*)&tree[kt1 * 8 + 2 * hi];

  int buf = 0;
  for (int i = 0; i < nsteps; ++i) {
    int kt = kt0 + i;
    int ktn  = (kt + 1 < ktend) ? kt + 1 : ktend - 1;
    int ktnn = (kt + 2 < ktend) ? kt + 2 : ktend - 1;
    // --- 1. stage step i (all data already in regs — minimal pre-barrier path)
    *(float4*)&As[buf][srow      ][scol] = ar0;
    *(float4*)&As[buf][srow +  64][scol] = ar1;
    *(float4*)&As[buf][srow + 128][scol] = ar2;
    *(float4*)&As[buf][srow + 192][scol] = ar3;
    *(ushort8*)&Bs[buf][w * 16 + fr][kq] = V;
    // --- 2. prefetch A(i+1)
    int k0n = ktn * 32;
    float4 arn0 = *(const float4*)(Ag + k0n);
    float4 arn1 = *(const float4*)(Ag + (size_t)64 * KDIM + k0n);
    float4 arn2 = *(const float4*)(Ag + (size_t)128 * KDIM + k0n);
    float4 arn3 = *(const float4*)(Ag + (size_t)192 * KDIM + k0n);
    __syncthreads();          // dbuf + 1 barrier (race-free per R6/R8 argument)
    // --- 3. main-MFMA fragment reads (issue early, in flight during logsig)
    bf16x8 a[4], b[4];
#pragma unroll
    for (int m = 0; m < 4; ++m) a[m] = *(const bf16x8*)&As[buf][w * 64 + m * 16 + fr][kq];
#pragma unroll
    for (int n = 0; n < 4; ++n) b[n] = *(const bf16x8*)&Bs[buf][n * 16 + fr][kq];
    // --- 4. logit MFMA for step i+1 (reg-only; co-issues with ds_read waits)
    f32x4 lacc = (f32x4){0.f, 0.f, 0.f, 0.f};
    lacc = __builtin_amdgcn_mfma_f32_16x16x32_bf16(wf0, zf0, lacc, 0, 0, 0);
    lacc = __builtin_amdgcn_mfma_f32_16x16x32_bf16(wf1, zf1, lacc, 0, 0, 0);
    // --- 5. prefetch W/bias/tree for step i+2
    const unsigned short* wpn = Wt + (size_t)(ktnn * 16 + fr) * 64 + kq;
    bf16x8 wfn0 = *(const bf16x8*)wpn;
    bf16x8 wfn1 = *(const bf16x8*)(wpn + 32);
    float4 b4n  = *(const float4*)&bias[ktnn * 16 + 4 * hi];
    int2   tr2n = *(const int2*)&tree[ktnn * 8 + 2 * hi];
    // --- 6. logsig(i+1) — VALU chain interleaves with main MFMAs (dual pipe)
    float bb[4] = { b4.x, b4.y, b4.z, b4.w };
    int tt[2] = { tr2.x, tr2.y };
    union { unsigned u[4]; ushort8 v; } VV;
#pragma unroll
    for (int p = 0; p < 2; ++p) {
      float l1 = lacc[2 * p + 1] + bb[2 * p + 1];
      float l0 = (tt[p] == -1) ? l1 : (lacc[2 * p] + bb[2 * p]);
      // logsig(v) = v>=0 ? -log(1+e^-v) : v - log(1+e^v);  logsig(-v) = logsig(v) - v
      float e0 = __expf(-fabsf(l0)); float sp0 = __logf(1.f + e0);
      float ls0 = (l0 >= 0.f) ? -sp0 : l0 - sp0;
      float e1 = __expf(-fabsf(l1)); float sp1 = __logf(1.f + e1);
      float ls1 = (l1 >= 0.f) ? -sp1 : l1 - sp1;
      VV.u[2 * p + 0] = pkbf(ls0, ls1);
      VV.u[2 * p + 1] = pkbf(ls0 - l0, ls1 - l1);
    }
    // --- 7. main MFMA: 16 per wave
#pragma unroll
    for (int m = 0; m < 4; ++m)
#pragma unroll
      for (int n = 0; n < 4; ++n)
        acc[m][n] = __builtin_amdgcn_mfma_f32_16x16x32_bf16(a[m], b[n], acc[m][n], 0, 0, 0);
    // --- 8. rotate pipeline registers
    V = VV.v;
    wf0 = wfn0; wf1 = wfn1; b4 = b4n; tr2 = tr2n;
    ar0 = arn0; ar1 = arn1; ar2 = arn2; ar3 = arn3;
    buf ^= 1;
  }
  // C/D: col = lane&15 (n), row = (lane>>4)*4 + reg (m). bf16 partials, nt stores.
  int col = lane & 15, rq = hi * 4;
  unsigned short* Pp = part + (size_t)s * (256 * 4096) + (size_t)(w * 64) * 4096 + n0;
#pragma unroll
  for (int m = 0; m < 4; ++m)
#pragma unroll
    for (int n = 0; n < 4; ++n)
#pragma unroll
      for (int r = 0; r < 4; ++r)
        __builtin_nontemporal_store(f2bf(acc[m][n][r]),
                                    &Pp[(m * 16 + rq + r) * 4096 + n * 16 + col]);
}

// ---------------- Kernel 3: reduce 8 bf16 partials -> f32 d_out ----------------
__global__ __launch_bounds__(256) void reduce8(const unsigned short* __restrict__ part,
                                               float* __restrict__ out) {
  int t = blockIdx.x * 256 + threadIdx.x;  // 262144 threads x 4 cols
  f32x4 s = (f32x4){0.f, 0.f, 0.f, 0.f};
#pragma unroll
  for (int q = 0; q < 8; ++q) {
    const us4* p = (const us4*)&part[(size_t)q * (256 * 4096) + (size_t)t * 4];
    us4 v = __builtin_nontemporal_load(p);
    s[0] += __uint_as_float((unsigned)v[0] << 16);
    s[1] += __uint_as_float((unsigned)v[1] << 16);
    s[2] += __uint_as_float((unsigned)v[2] << 16);
    s[3] += __uint_as_float((unsigned)v[3] << 16);
  }
  f32x4* o = (f32x4*)&out[(size_t)t * 4];
  __builtin_nontemporal_store(s, o);
}

extern "C" void kernel_launch(void* const* d_in, const int* in_sizes, int n_in,
                              void* d_out, int out_size, void* d_ws, size_t ws_size,
                              hipStream_t stream) {
  const float* x    = (const float*)d_in[0];
  const float* z    = (const float*)d_in[1];
  const float* W    = (const float*)d_in[2];
  const float* bias = (const float*)d_in[3];
  const int*   tree = (const int*)d_in[4];
  float* out = (float*)d_out;

  unsigned short* Amat = (unsigned short*)d_ws;                     //  1,605,632 B
  unsigned short* Wt   = (unsigned short*)((char*)d_ws + 1605632);  //    200,704 B
  unsigned short* part = (unsigned short*)((char*)d_ws + 1806336);  // 16,777,216 B (bf16)

  prep<<<dim3(1122), 256, 0, stream>>>(x, W, tree, Amat, Wt);
  gemm_fused<<<dim3(512), 256, 0, stream>>>(Amat, z, Wt, bias, tree, part);
  reduce8<<<dim3(1024), 256, 0, stream>>>(part, out);
}